// Round 9
// baseline (12838.527 us; speedup 1.0000x reference)
//
#include <hip/hip_runtime.h>
#include <hip/hip_bf16.h>
#include <stdint.h>

typedef unsigned short u16;
typedef unsigned int   u32;
typedef unsigned long long u64;

typedef __attribute__((ext_vector_type(4))) float  f32x4;
typedef __attribute__((ext_vector_type(8))) short  bf16x8;
typedef __attribute__((ext_vector_type(8))) unsigned short us8;

#define T_LEN 2048
#define BATCH 32
#define IDIM  512
#define HDIM  512
#define G4    2048
#define MARK  0x7FC0   // bf16 NaN — impossible output of sigm*tanh (both clamped finite)

// workspace layout (bytes)
#define XBF_OFF   0ull            // bf16 x : 67108864 B (dead after gemm_xp)
#define WIH_OFF   67108864ull     // bf16 wih[2][2048][512] (dead after gemm_xp)
#define HBUF_OFF  67108864ull     // h_hist bf16 [2][4][32][512] = 256 KiB, reuses WIH region
#define WHH_OFF   71303168ull     // bf16 whh[2][2048][512]
#define XP_OFF    75497472ull     // bf16 xp[2][T][w:32][u:16][g:4][b:32]
#define WS_NEED   612499968ull

__device__ __forceinline__ u16 f2bf(float f) {
  u32 u = __float_as_uint(f);
  return (u16)((u + 0x7FFFu + ((u >> 16) & 1u)) >> 16);   // RTNE
}
__device__ __forceinline__ float bf2f(u16 h) {
  return __uint_as_float(((u32)h) << 16);
}
__device__ __forceinline__ float sigm(float x) {
  x = fminf(fmaxf(x, -30.f), 30.f);
  return 1.f / (1.f + __expf(-x));
}
__device__ __forceinline__ float tanh_(float x) {
  x = fminf(fmaxf(x, -15.f), 15.f);
  float e = __expf(2.f * x);
  return (e - 1.f) / (e + 1.f);
}

// ---------------- prep: fp32 -> bf16 conversions (x, weights) ----------------
__global__ __launch_bounds__(256) void prep_kernel(
    const float4* __restrict__ x,
    const float4* __restrict__ wihf, const float4* __restrict__ wihb,
    const float4* __restrict__ whhf, const float4* __restrict__ whhb,
    ushort4* __restrict__ xbf, ushort4* __restrict__ wihbf,
    ushort4* __restrict__ whhbf)
{
  const size_t NX = 8388608, NW = 262144;   // float4 units
  const size_t total = NX + 4 * NW;
  size_t stride = (size_t)gridDim.x * blockDim.x;
  for (size_t i = (size_t)blockIdx.x * blockDim.x + threadIdx.x; i < total; i += stride) {
    const float4* src; ushort4* dst; size_t off;
    if (i < NX)                { src = x;    dst = xbf;          off = i; }
    else if (i < NX + NW)      { src = wihf; dst = wihbf;        off = i - NX; }
    else if (i < NX + 2 * NW)  { src = wihb; dst = wihbf + NW;   off = i - NX - NW; }
    else if (i < NX + 3 * NW)  { src = whhf; dst = whhbf;        off = i - NX - 2 * NW; }
    else                       { src = whhb; dst = whhbf + NW;   off = i - NX - 3 * NW; }
    float4 v = src[off];
    ushort4 o;
    o.x = f2bf(v.x); o.y = f2bf(v.y); o.z = f2bf(v.z); o.w = f2bf(v.w);
    dst[off] = o;
  }
}

// ---------------- prep2 (runs AFTER gemm_xp): seed h_hist into dead WIH region ------------
// layout: hbuf[dir:2][slot:4][32][512] bf16. slot0 = h0, slots 1..3 = MARK.
__global__ __launch_bounds__(256) void prep2_kernel(
    const float4* __restrict__ h0f, const float4* __restrict__ h0b,
    ushort4* __restrict__ hbuf)
{
  size_t i = (size_t)blockIdx.x * blockDim.x + threadIdx.x;   // 32768 ushort4 total
  if (i >= 32768) return;
  const size_t NH = 4096;          // ushort4 per h0 (32*512 u16)
  const size_t DIR = 16384;        // ushort4 per direction (4 slots)
  size_t d = i / DIR, r = i % DIR;
  ushort4 o;
  if (r < NH) {
    float4 v = (d ? h0b : h0f)[r];
    o.x = f2bf(v.x); o.y = f2bf(v.y); o.z = f2bf(v.z); o.w = f2bf(v.w);
  } else {
    o.x = MARK; o.y = MARK; o.z = MARK; o.w = MARK;
  }
  hbuf[i] = o;
}

// ---------------- x-projection GEMM: xp = x @ Wih^T + b (both dirs), permuted store --------
// Store layout per t: [w:32][u:16][g:4][b:32];  col = g*512 + w*16 + u.
__global__ __launch_bounds__(256, 2) void gemm_xp(
    const u16* __restrict__ xbf, const u16* __restrict__ wihbf,
    const float* __restrict__ bias_f, const float* __restrict__ bias_b,
    u16* __restrict__ xpo)
{
  const int m0 = blockIdx.x * 128;
  const int n0 = blockIdx.y * 128;
  const int dir = blockIdx.z;
  const int tid = threadIdx.x, l = tid & 63, wv = tid >> 6;

  __shared__ u16 As[128 * 72];
  __shared__ u16 Bs[128 * 72];

  const u16* wih = wihbf + (size_t)dir * G4 * IDIM;

  f32x4 acc[4][4];
#pragma unroll
  for (int i = 0; i < 4; i++)
#pragma unroll
    for (int j = 0; j < 4; j++) acc[i][j] = (f32x4){0.f, 0.f, 0.f, 0.f};

  const int srow = tid >> 1, shalf = tid & 1;
  const int wr = wv >> 1, wc = wv & 1;

  for (int k0 = 0; k0 < IDIM; k0 += 64) {
    __syncthreads();
    {
      const u16* ag = xbf + (size_t)(m0 + srow) * IDIM + k0 + shalf * 32;
      const u16* bg = wih + (size_t)(n0 + srow) * IDIM + k0 + shalf * 32;
      u16* ad = &As[srow * 72 + shalf * 32];
      u16* bd = &Bs[srow * 72 + shalf * 32];
#pragma unroll
      for (int q = 0; q < 4; q++) *(us8*)(ad + q * 8) = *(const us8*)(ag + q * 8);
#pragma unroll
      for (int q = 0; q < 4; q++) *(us8*)(bd + q * 8) = *(const us8*)(bg + q * 8);
    }
    __syncthreads();
#pragma unroll
    for (int kk = 0; kk < 2; kk++) {
      bf16x8 af[4], bv[4];
#pragma unroll
      for (int i = 0; i < 4; i++)
        af[i] = *(const bf16x8*)&As[(wr * 64 + i * 16 + (l & 15)) * 72 + kk * 32 + (l >> 4) * 8];
#pragma unroll
      for (int j = 0; j < 4; j++)
        bv[j] = *(const bf16x8*)&Bs[(wc * 64 + j * 16 + (l & 15)) * 72 + kk * 32 + (l >> 4) * 8];
#pragma unroll
      for (int i = 0; i < 4; i++)
#pragma unroll
        for (int j = 0; j < 4; j++)
          acc[i][j] = __builtin_amdgcn_mfma_f32_16x16x32_bf16(af[i], bv[j], acc[i][j], 0, 0, 0);
    }
  }

  const float* bias = dir ? bias_b : bias_f;
  const size_t dirbase = (size_t)dir * T_LEN * 65536ull;
#pragma unroll
  for (int j = 0; j < 4; j++) {
    int col = n0 + wc * 64 + j * 16 + (l & 15);
    float bb = bias[col];
    // col = g*512 + w*16 + u  ->  [w:32][u:16][g:4][b:32]
    size_t coloff = (size_t)((col >> 4) & 31) * 2048 + (size_t)(col & 15) * 128
                  + (size_t)(col >> 9) * 32;
#pragma unroll
    for (int i = 0; i < 4; i++) {
#pragma unroll
      for (int r = 0; r < 4; r++) {
        int row = m0 + wr * 64 + i * 16 + (l >> 4) * 4 + r;
        int t = row >> 5, b = row & 31;
        xpo[dirbase + (size_t)t * 65536 + coloff + (size_t)b] = f2bf(acc[i][j][r] + bb);
      }
    }
  }
}

// ---------------- persistent recurrent scan: wave-autonomous, ZERO barriers --------------
// 64 WGs: dir = bid>>5, w = bid&31. 4 waves = (mt: batch-half) x (nt: unit-octet).
// Wave owns batches mt*16..+15 x units w*16+nt*8..+8, FULL K=512 in-wave:
// poll LOAD16 -> 32 MFMA -> shfl_xor(8) gate gather -> in-register elementwise ->
// intra-wave LDS transpose -> 16B publish + clears. No __syncthreads in the loop.
// Protocol soundness: identical data-is-the-flag (R4/R6); each step's poll ends in
// vmcnt(0), draining this wave's prior clear/publish stores (vmcnt counts stores),
// preserving the clear -> publish -> consumer-catch happens-before chain.
__global__ __launch_bounds__(256, 1) void lstm_scan(
    const u16* __restrict__ xp, const u16* __restrict__ whhbf,
    const float* __restrict__ c0f, const float* __restrict__ c0b,
    u16* hbuf, float* __restrict__ out)
{
  const int bid = blockIdx.x;
  const int dir = bid >> 5;
  const int w   = bid & 31;
  const int tid = threadIdx.x, l = tid & 63, wv = tid >> 6;
  const int mt = wv >> 1, nt = wv & 1;        // batch-half, unit-octet
  const int grp = l >> 4, lr = l & 15;
  const int role = lr >> 3, u = lr & 7;       // role 0: gates {i,g}; role 1: {f,o}

  __shared__ __align__(16) u16 tp[4][16][8];  // per-wave transpose tile [wave][batch][unit]

  // Whh fragments in registers: tile t -> gate t*2+role; full K (16 subtiles)
  bf16x8 bfr0[16], bfr1[16];
  {
    const u16* wr0 = whhbf + ((size_t)dir * G4 + (size_t)(role) * 512
                   + w * 16 + nt * 8 + u) * 512 + grp * 8;
    const u16* wr1 = whhbf + ((size_t)dir * G4 + (size_t)(2 + role) * 512
                   + w * 16 + nt * 8 + u) * 512 + grp * 8;
#pragma unroll
    for (int kk = 0; kk < 16; kk++) {
      bfr0[kk] = *(const bf16x8*)(wr0 + kk * 32);
      bfr1[kk] = *(const bf16x8*)(wr1 + kk * 32);
    }
  }

  // c-state: 4 batches (mt*16+grp*4+r) x 1 unit, register-resident (role-duplicated)
  const float* c0 = dir ? c0b : c0f;
  float cc[4];
#pragma unroll
  for (int r = 0; r < 4; r++)
    cc[r] = c0[(size_t)(mt * 16 + grp * 4 + r) * 512 + w * 16 + nt * 8 + u];

  u16* hb = hbuf + (size_t)dir * 4 * BATCH * HDIM;   // 4 slots
  const u16* xpd = xp + (size_t)dir * T_LEN * 65536ull;
  const int arow = mt * 16 + lr;

  bf16x8 mkv;
#pragma unroll
  for (int q = 0; q < 8; q++) mkv[q] = (short)MARK;

#define LOAD16                                                             \
    asm volatile(                                                          \
      "global_load_dwordx4 %0, %16, off sc0 sc1\n\t"                       \
      "global_load_dwordx4 %1, %16, off offset:64 sc0 sc1\n\t"             \
      "global_load_dwordx4 %2, %16, off offset:128 sc0 sc1\n\t"            \
      "global_load_dwordx4 %3, %16, off offset:192 sc0 sc1\n\t"            \
      "global_load_dwordx4 %4, %16, off offset:256 sc0 sc1\n\t"            \
      "global_load_dwordx4 %5, %16, off offset:320 sc0 sc1\n\t"            \
      "global_load_dwordx4 %6, %16, off offset:384 sc0 sc1\n\t"            \
      "global_load_dwordx4 %7, %16, off offset:448 sc0 sc1\n\t"            \
      "global_load_dwordx4 %8, %16, off offset:512 sc0 sc1\n\t"            \
      "global_load_dwordx4 %9, %16, off offset:576 sc0 sc1\n\t"            \
      "global_load_dwordx4 %10, %16, off offset:640 sc0 sc1\n\t"           \
      "global_load_dwordx4 %11, %16, off offset:704 sc0 sc1\n\t"           \
      "global_load_dwordx4 %12, %16, off offset:768 sc0 sc1\n\t"           \
      "global_load_dwordx4 %13, %16, off offset:832 sc0 sc1\n\t"           \
      "global_load_dwordx4 %14, %16, off offset:896 sc0 sc1\n\t"           \
      "global_load_dwordx4 %15, %16, off offset:960 sc0 sc1\n\t"           \
      "s_waitcnt vmcnt(0)"                                                 \
      : "=&v"(afr[0]), "=&v"(afr[1]), "=&v"(afr[2]), "=&v"(afr[3]),        \
        "=&v"(afr[4]), "=&v"(afr[5]), "=&v"(afr[6]), "=&v"(afr[7]),        \
        "=&v"(afr[8]), "=&v"(afr[9]), "=&v"(afr[10]), "=&v"(afr[11]),      \
        "=&v"(afr[12]), "=&v"(afr[13]), "=&v"(afr[14]), "=&v"(afr[15])     \
      : "v"(pbase) : "memory")

  for (int k = 1; k <= T_LEN; k++) {
    const int t = dir ? (T_LEN - k) : (k - 1);

    // xp prefetch: 4 gates x 4 batches (u64 each), layout [w][u][g][b]
    const u16* xb = xpd + (size_t)t * 65536 + (size_t)w * 2048
                  + (size_t)(nt * 8 + u) * 128 + mt * 16 + grp * 4;
    u64 xq0 = *(const u64*)(xb);
    u64 xq1 = *(const u64*)(xb + 32);
    u64 xq2 = *(const u64*)(xb + 64);
    u64 xq3 = *(const u64*)(xb + 96);

    // poll-load h_{k-1}: 16 x 16B chunks (full K), single-store chunks, masked retry
    const u16* pbase = hb + (size_t)((k - 1) & 3) * (BATCH * HDIM)
                     + (size_t)arow * 512 + grp * 8;
    bf16x8 afr[16];
    LOAD16;
    for (;;) {
      int bad = 0;
#pragma unroll
      for (int q = 0; q < 16; q++) bad |= (afr[q][0] == (short)MARK);
      if (!__any(bad)) break;
      __builtin_amdgcn_s_sleep(1);
      if (bad) { LOAD16; }
    }
    __builtin_amdgcn_sched_barrier(0);

    // clears: own publish slice in slot (k+2)&3 (holds h_{k-2}; all reads done — R6 proof)
    if (l < 16) {
      u16* cdst = hb + (size_t)((k + 2) & 3) * (BATCH * HDIM)
                + (size_t)(mt * 16 + l) * 512 + w * 16 + nt * 8;
      asm volatile("global_store_dwordx4 %0, %1, off sc0 sc1" :: "v"(cdst), "v"(mkv) : "memory");
    }

    // full-K MFMA: 2 accumulator tiles (gates {i,f} interleaved by role, {g,o}) x 16 subtiles
    f32x4 a0 = (f32x4){0.f, 0.f, 0.f, 0.f};
    f32x4 a1 = (f32x4){0.f, 0.f, 0.f, 0.f};
#pragma unroll
    for (int kk = 0; kk < 16; kk++) {
      a0 = __builtin_amdgcn_mfma_f32_16x16x32_bf16(afr[kk], bfr0[kk], a0, 0, 0, 0);
      a1 = __builtin_amdgcn_mfma_f32_16x16x32_bf16(afr[kk], bfr1[kk], a1, 0, 0, 0);
    }

    // gate gather: lane pair l <-> l^8 holds {i,g} / {f,o}; elementwise in-register
    u16 hu[4];
    float hf[4];
#pragma unroll
    for (int r = 0; r < 4; r++) {
      float own0 = a0[r], own1 = a1[r];
      float oth0 = __shfl_xor(own0, 8);
      float oth1 = __shfl_xor(own1, 8);
      float gi = role ? oth0 : own0;
      float gf = role ? own0 : oth0;
      float gg = role ? oth1 : own1;
      float go = role ? own1 : oth1;
      gi += bf2f((u16)(xq0 >> (16 * r)));
      gf += bf2f((u16)(xq1 >> (16 * r)));
      gg += bf2f((u16)(xq2 >> (16 * r)));
      go += bf2f((u16)(xq3 >> (16 * r)));
      float si = sigm(gi), sf_ = sigm(gf), sg = tanh_(gg), so = sigm(go);
      cc[r] = sf_ * cc[r] + si * sg;
      float h = so * tanh_(cc[r]);
      hu[r] = f2bf(h);
      hf[r] = h;
    }

    // intra-wave LDS transpose -> 16B rows [batch][8 units] (same-wave LDS is ordered)
    if (role == 0) {
#pragma unroll
      for (int r = 0; r < 4; r++) tp[wv][grp * 4 + r][u] = hu[r];
    }
    asm volatile("s_waitcnt lgkmcnt(0)" ::: "memory");

    if (l < 16) {   // publish h_k: one 16B store per batch row of this wave's slice
      bf16x8 hv = *(const bf16x8*)&tp[wv][l][0];
      u16* dstp = hb + (size_t)(k & 3) * (BATCH * HDIM)
                + (size_t)(mt * 16 + l) * 512 + w * 16 + nt * 8;
      asm volatile("global_store_dwordx4 %0, %1, off sc0 sc1" :: "v"(dstp), "v"(hv) : "memory");
    }

    if (role == 1) {   // fp32 output from registers, off the critical path
      size_t ob = ((size_t)t * 32 + mt * 16 + grp * 4) * 1024
                + (size_t)dir * 512 + w * 16 + nt * 8 + u;
#pragma unroll
      for (int r = 0; r < 4; r++) out[ob + (size_t)r * 1024] = hf[r];
    }
  }
#undef LOAD16
}

// ---------------------------------------------------------------------------------------
extern "C" void kernel_launch(void* const* d_in, const int* in_sizes, int n_in,
                              void* d_out, int out_size, void* d_ws, size_t ws_size,
                              hipStream_t stream) {
  if (ws_size < WS_NEED) return;

  const float* x     = (const float*)d_in[0];
  const float* h0_f  = (const float*)d_in[1];
  const float* c0_f  = (const float*)d_in[2];
  const float* h0_b  = (const float*)d_in[3];
  const float* c0_b  = (const float*)d_in[4];
  const float* Wih_f = (const float*)d_in[5];
  const float* Whh_f = (const float*)d_in[6];
  const float* b_f   = (const float*)d_in[7];
  const float* Wih_b = (const float*)d_in[8];
  const float* Whh_b = (const float*)d_in[9];
  const float* b_b   = (const float*)d_in[10];

  char* ws = (char*)d_ws;
  u16* xbf   = (u16*)(ws + XBF_OFF);
  u16* wihbf = (u16*)(ws + WIH_OFF);
  u16* whhbf = (u16*)(ws + WHH_OFF);
  u16* xpw   = (u16*)(ws + XP_OFF);
  u16* hbuf  = (u16*)(ws + HBUF_OFF);   // overlays WIH region (dead after gemm_xp)

  prep_kernel<<<4096, 256, 0, stream>>>(
      (const float4*)x, (const float4*)Wih_f, (const float4*)Wih_b,
      (const float4*)Whh_f, (const float4*)Whh_b,
      (ushort4*)xbf, (ushort4*)wihbf, (ushort4*)whhbf);

  dim3 g2(512, 16, 2);
  gemm_xp<<<g2, 256, 0, stream>>>(xbf, wihbf, b_f, b_b, xpw);

  prep2_kernel<<<128, 256, 0, stream>>>(
      (const float4*)h0_f, (const float4*)h0_b, (ushort4*)hbuf);

  lstm_scan<<<64, 256, 0, stream>>>(xpw, whhbf, c0_f, c0_b, hbuf, (float*)d_out);
}

// Round 10
// 8803.662 us; speedup vs baseline: 1.4583x; 1.4583x over previous
//
#include <hip/hip_runtime.h>
#include <hip/hip_bf16.h>
#include <stdint.h>

typedef unsigned short u16;
typedef unsigned int   u32;
typedef unsigned long long u64;

typedef __attribute__((ext_vector_type(4))) float  f32x4;
typedef __attribute__((ext_vector_type(8))) short  bf16x8;
typedef __attribute__((ext_vector_type(8))) unsigned short us8;

#define T_LEN 2048
#define BATCH 32
#define IDIM  512
#define HDIM  512
#define G4    2048
#define MARK  0x7FC0   // bf16 NaN — impossible output of sigm*tanh (both clamped finite)

// workspace layout (bytes)
#define XBF_OFF   0ull            // bf16 x : 67108864 B (dead after gemm_xp)
#define WIH_OFF   67108864ull     // bf16 wih[2][2048][512] (dead after gemm_xp)
#define HBUF_OFF  67108864ull     // h_hist bf16 [2][4][32][512] = 256 KiB, reuses WIH region
#define WHH_OFF   71303168ull     // bf16 whh[2][2048][512]
#define XP_OFF    75497472ull     // bf16 xp[2][T][w:32][b:32][g:4][u:16]
#define WS_NEED   612499968ull

__device__ __forceinline__ u16 f2bf(float f) {
  u32 u = __float_as_uint(f);
  return (u16)((u + 0x7FFFu + ((u >> 16) & 1u)) >> 16);   // RTNE
}
__device__ __forceinline__ float bf2f(u16 h) {
  return __uint_as_float(((u32)h) << 16);
}
__device__ __forceinline__ float sigm(float x) {
  x = fminf(fmaxf(x, -30.f), 30.f);
  return 1.f / (1.f + __expf(-x));
}
__device__ __forceinline__ float tanh_(float x) {
  x = fminf(fmaxf(x, -15.f), 15.f);
  float e = __expf(2.f * x);
  return (e - 1.f) / (e + 1.f);
}

// ---------------- prep: fp32 -> bf16 conversions (x, weights) ----------------
__global__ __launch_bounds__(256) void prep_kernel(
    const float4* __restrict__ x,
    const float4* __restrict__ wihf, const float4* __restrict__ wihb,
    const float4* __restrict__ whhf, const float4* __restrict__ whhb,
    ushort4* __restrict__ xbf, ushort4* __restrict__ wihbf,
    ushort4* __restrict__ whhbf)
{
  const size_t NX = 8388608, NW = 262144;   // float4 units
  const size_t total = NX + 4 * NW;
  size_t stride = (size_t)gridDim.x * blockDim.x;
  for (size_t i = (size_t)blockIdx.x * blockDim.x + threadIdx.x; i < total; i += stride) {
    const float4* src; ushort4* dst; size_t off;
    if (i < NX)                { src = x;    dst = xbf;          off = i; }
    else if (i < NX + NW)      { src = wihf; dst = wihbf;        off = i - NX; }
    else if (i < NX + 2 * NW)  { src = wihb; dst = wihbf + NW;   off = i - NX - NW; }
    else if (i < NX + 3 * NW)  { src = whhf; dst = whhbf;        off = i - NX - 2 * NW; }
    else                       { src = whhb; dst = whhbf + NW;   off = i - NX - 3 * NW; }
    float4 v = src[off];
    ushort4 o;
    o.x = f2bf(v.x); o.y = f2bf(v.y); o.z = f2bf(v.z); o.w = f2bf(v.w);
    dst[off] = o;
  }
}

// ---------------- prep2 (runs AFTER gemm_xp): seed h_hist into dead WIH region ------------
// layout: hbuf[dir:2][slot:4][32][512] bf16. slot0 = h0, slots 1..3 = MARK.
__global__ __launch_bounds__(256) void prep2_kernel(
    const float4* __restrict__ h0f, const float4* __restrict__ h0b,
    ushort4* __restrict__ hbuf)
{
  size_t i = (size_t)blockIdx.x * blockDim.x + threadIdx.x;   // 32768 ushort4 total
  if (i >= 32768) return;
  const size_t NH = 4096;          // ushort4 per h0 (32*512 u16)
  const size_t DIR = 16384;        // ushort4 per direction (4 slots)
  size_t d = i / DIR, r = i % DIR;
  ushort4 o;
  if (r < NH) {
    float4 v = (d ? h0b : h0f)[r];
    o.x = f2bf(v.x); o.y = f2bf(v.y); o.z = f2bf(v.z); o.w = f2bf(v.w);
  } else {
    o.x = MARK; o.y = MARK; o.z = MARK; o.w = MARK;
  }
  hbuf[i] = o;
}

// ---------------- x-projection GEMM: xp = x @ Wih^T + b (both dirs), permuted store --------
// Store layout per t: [w:32][b:32][g:4][u:16];  col = g*512 + w*16 + u. (R6-proven.)
__global__ __launch_bounds__(256, 2) void gemm_xp(
    const u16* __restrict__ xbf, const u16* __restrict__ wihbf,
    const float* __restrict__ bias_f, const float* __restrict__ bias_b,
    u16* __restrict__ xpo)
{
  const int m0 = blockIdx.x * 128;
  const int n0 = blockIdx.y * 128;
  const int dir = blockIdx.z;
  const int tid = threadIdx.x, l = tid & 63, wv = tid >> 6;

  __shared__ u16 As[128 * 72];
  __shared__ u16 Bs[128 * 72];

  const u16* wih = wihbf + (size_t)dir * G4 * IDIM;

  f32x4 acc[4][4];
#pragma unroll
  for (int i = 0; i < 4; i++)
#pragma unroll
    for (int j = 0; j < 4; j++) acc[i][j] = (f32x4){0.f, 0.f, 0.f, 0.f};

  const int srow = tid >> 1, shalf = tid & 1;
  const int wr = wv >> 1, wc = wv & 1;

  for (int k0 = 0; k0 < IDIM; k0 += 64) {
    __syncthreads();
    {
      const u16* ag = xbf + (size_t)(m0 + srow) * IDIM + k0 + shalf * 32;
      const u16* bg = wih + (size_t)(n0 + srow) * IDIM + k0 + shalf * 32;
      u16* ad = &As[srow * 72 + shalf * 32];
      u16* bd = &Bs[srow * 72 + shalf * 32];
#pragma unroll
      for (int q = 0; q < 4; q++) *(us8*)(ad + q * 8) = *(const us8*)(ag + q * 8);
#pragma unroll
      for (int q = 0; q < 4; q++) *(us8*)(bd + q * 8) = *(const us8*)(bg + q * 8);
    }
    __syncthreads();
#pragma unroll
    for (int kk = 0; kk < 2; kk++) {
      bf16x8 af[4], bv[4];
#pragma unroll
      for (int i = 0; i < 4; i++)
        af[i] = *(const bf16x8*)&As[(wr * 64 + i * 16 + (l & 15)) * 72 + kk * 32 + (l >> 4) * 8];
#pragma unroll
      for (int j = 0; j < 4; j++)
        bv[j] = *(const bf16x8*)&Bs[(wc * 64 + j * 16 + (l & 15)) * 72 + kk * 32 + (l >> 4) * 8];
#pragma unroll
      for (int i = 0; i < 4; i++)
#pragma unroll
        for (int j = 0; j < 4; j++)
          acc[i][j] = __builtin_amdgcn_mfma_f32_16x16x32_bf16(af[i], bv[j], acc[i][j], 0, 0, 0);
    }
  }

  const float* bias = dir ? bias_b : bias_f;
  const size_t dirbase = (size_t)dir * T_LEN * 65536ull;
#pragma unroll
  for (int j = 0; j < 4; j++) {
    int col = n0 + wc * 64 + j * 16 + (l & 15);
    float bb = bias[col];
    // col = g*512 + w*16 + u  ->  [w:32][b:32][g:4][u:16]
    size_t coloff = (size_t)((col >> 4) & 31) * 2048 + (size_t)(col >> 9) * 16 + (size_t)(col & 15);
#pragma unroll
    for (int i = 0; i < 4; i++) {
#pragma unroll
      for (int r = 0; r < 4; r++) {
        int row = m0 + wr * 64 + i * 16 + (l >> 4) * 4 + r;
        int t = row >> 5, b = row & 31;
        xpo[dirbase + (size_t)t * 65536 + coloff + (size_t)b * 64] = f2bf(acc[i][j][r] + bb);
      }
    }
  }
}

// ---------------- persistent recurrent scan: R6 structure + dual-stream poll -------------
// 64 WGs: dir = bid>>5, w = bid&31. WG owns 16 hidden units x 32 batches.
// Whh in registers; 4 waves = (mt: batch-half) x (kh: K-half); Gl LDS K-reduce.
// Poll: TWO interleaved LOAD8 streams, counted vmcnt(8) waits (sample period ~RT/2).
// Soundness: slot k-1 is immutable during our poll (its clear happens at producers'
// step k+1, which transitively requires OUR step-k publish) -> monotone; probe-clean
// exit implies primary stream (masked-reissued) clean; final vmcnt(0) collects strays.
// Tail: elementwise all 256 thr -> Hp (wave-local rows) -> lgkmcnt(0) (wave scope,
// NO barrier) -> lanes 0-15 publish own 8 rows (16B, chunk-sound); lanes 16-31 issued
// clears right after poll-catch. barrier1 (Gl) + barrier2 (throttle) per step.
__global__ __launch_bounds__(256, 1) void lstm_scan(
    const u16* __restrict__ xp, const u16* __restrict__ whhbf,
    const float* __restrict__ c0f, const float* __restrict__ c0b,
    u16* hbuf, float* __restrict__ out)
{
  const int bid = blockIdx.x;
  const int dir = bid >> 5;
  const int w   = bid & 31;
  const int tid = threadIdx.x, l = tid & 63, wv = tid >> 6;
  const int mt = wv >> 1, kh = wv & 1;        // batch-half, K-half
  const int grp = l >> 4, lr = l & 15;

  __shared__ float Gl[2][32][68];             // [kh][batch][g*16+u], padded
  __shared__ __align__(16) u16 Hp[512];       // [b][u:16]

  // Whh fragments straight to registers: gate g, K-subtile kk (this wave's K-half)
  bf16x8 bfr[4][8];
#pragma unroll
  for (int g = 0; g < 4; g++) {
    const u16* wrow = whhbf + ((size_t)dir * G4 + (size_t)g * 512 + w * 16 + lr) * 512
                    + kh * 256 + grp * 8;
#pragma unroll
    for (int kk = 0; kk < 8; kk++)
      bfr[g][kk] = *(const bf16x8*)(wrow + kk * 32);
  }

  // elementwise role: batch b_, units u0 and u0+8 (b_ = tid>>3 -> wave-local rows!)
  const int b_ = tid >> 3, u0 = tid & 7;
  const float* c0 = dir ? c0b : c0f;
  float cA = c0[b_ * 512 + w * 16 + u0];
  float cB = c0[b_ * 512 + w * 16 + u0 + 8];

  u16* hb = hbuf + (size_t)dir * 4 * BATCH * HDIM;   // 4 slots
  const u16* xpd = xp + (size_t)dir * T_LEN * 65536ull;
  const int arow = mt * 16 + lr;

  bf16x8 mkv;
#pragma unroll
  for (int q = 0; q < 8; q++) mkv[q] = (short)MARK;

#define LOAD8(A)                                                           \
    asm volatile(                                                          \
      "global_load_dwordx4 %0, %8, off sc0 sc1\n\t"                        \
      "global_load_dwordx4 %1, %8, off offset:64 sc0 sc1\n\t"              \
      "global_load_dwordx4 %2, %8, off offset:128 sc0 sc1\n\t"             \
      "global_load_dwordx4 %3, %8, off offset:192 sc0 sc1\n\t"             \
      "global_load_dwordx4 %4, %8, off offset:256 sc0 sc1\n\t"             \
      "global_load_dwordx4 %5, %8, off offset:320 sc0 sc1\n\t"             \
      "global_load_dwordx4 %6, %8, off offset:384 sc0 sc1\n\t"             \
      "global_load_dwordx4 %7, %8, off offset:448 sc0 sc1"                 \
      : "=&v"(A[0]), "=&v"(A[1]), "=&v"(A[2]), "=&v"(A[3]),                \
        "=&v"(A[4]), "=&v"(A[5]), "=&v"(A[6]), "=&v"(A[7])                 \
      : "v"(pbase) : "memory")
#define WAITV(N)                                                           \
    asm volatile("s_waitcnt vmcnt(" #N ")" ::: "memory");                  \
    __builtin_amdgcn_sched_barrier(0)

  for (int k = 1; k <= T_LEN; k++) {
    const int t = dir ? (T_LEN - k) : (k - 1);

    // xp prefetch: 8 gate pre-activations (units u0, u0+8), plain cached loads
    const u16* xb = xpd + (size_t)t * 65536 + (size_t)w * 2048 + (size_t)b_ * 64 + u0;
    u16 xi0 = xb[0],  xiB = xb[8];
    u16 xf0 = xb[16], xfB = xb[24];
    u16 xg0 = xb[32], xgB = xb[40];
    u16 xo0 = xb[48], xoB = xb[56];

    // ---- dual-stream poll of h_{k-1} (8 x 16B chunks per stream) ----
    const u16* pbase = hb + (size_t)((k - 1) & 3) * (BATCH * HDIM)
                     + (size_t)arow * 512 + kh * 256 + grp * 8;
    bf16x8 afr[8], prb[8];
    LOAD8(afr);
    LOAD8(prb);
    for (;;) {
      WAITV(8);                                  // primary stream landed
      int bad = 0;
#pragma unroll
      for (int q = 0; q < 8; q++) bad |= (afr[q][0] == (short)MARK);
      if (!__any(bad)) break;
      if (bad) { LOAD8(afr); }                   // masked reissue (stragglers only)
      WAITV(8);                                  // probe stream landed
      int bad2 = 0;
#pragma unroll
      for (int q = 0; q < 8; q++) bad2 |= (prb[q][0] == (short)MARK);
      if (!__any(bad2)) break;                   // monotone => afr (reissued) also clean
      if (bad2) { LOAD8(prb); }
    }
    WAITV(0);                                    // collect strays; afr fully valid

    // clears off the critical path (lanes 16..31 of each wave): own rows, slot (k+2)&3
    if (lr >= 8 && grp >= 2) { /* never: keep lane predicate simple below */ }
    if (l >= 16 && l < 32) {
      int li = l - 16;
      u16* cdst = hb + (size_t)((k + 2) & 3) * (BATCH * HDIM)
                + (size_t)(wv * 8 + (li >> 1)) * 512 + w * 16 + (li & 1) * 8;
      asm volatile("global_store_dwordx4 %0, %1, off sc0 sc1" :: "v"(cdst), "v"(mkv) : "memory");
    }

    // MFMA: 4 gate-tiles x 8 K-subtiles (this wave's K-half)
    f32x4 acc[4];
#pragma unroll
    for (int g = 0; g < 4; g++) acc[g] = (f32x4){0.f, 0.f, 0.f, 0.f};
#pragma unroll
    for (int kk = 0; kk < 8; kk++) {
#pragma unroll
      for (int g = 0; g < 4; g++)
        acc[g] = __builtin_amdgcn_mfma_f32_16x16x32_bf16(afr[kk], bfr[g][kk], acc[g], 0, 0, 0);
    }
#pragma unroll
    for (int g = 0; g < 4; g++)
#pragma unroll
      for (int r = 0; r < 4; r++)
        Gl[kh][mt * 16 + grp * 4 + r][g * 16 + lr] = acc[g][r];
    __syncthreads();                               // barrier 1: partial gates ready

    // elementwise: two units per thread (R6-verbatim math)
    float ai = Gl[0][b_][u0]      + Gl[1][b_][u0]      + bf2f(xi0);
    float af = Gl[0][b_][16 + u0] + Gl[1][b_][16 + u0] + bf2f(xf0);
    float ag = Gl[0][b_][32 + u0] + Gl[1][b_][32 + u0] + bf2f(xg0);
    float ao = Gl[0][b_][48 + u0] + Gl[1][b_][48 + u0] + bf2f(xo0);
    float si = sigm(ai), sf_ = sigm(af), sg = tanh_(ag), so = sigm(ao);
    cA = sf_ * cA + si * sg;
    float hA = so * tanh_(cA);

    const int u1 = u0 + 8;
    ai = Gl[0][b_][u1]      + Gl[1][b_][u1]      + bf2f(xiB);
    af = Gl[0][b_][16 + u1] + Gl[1][b_][16 + u1] + bf2f(xfB);
    ag = Gl[0][b_][32 + u1] + Gl[1][b_][32 + u1] + bf2f(xgB);
    ao = Gl[0][b_][48 + u1] + Gl[1][b_][48 + u1] + bf2f(xoB);
    si = sigm(ai); sf_ = sigm(af); sg = tanh_(ag); so = sigm(ao);
    cB = sf_ * cB + si * sg;
    float hB = so * tanh_(cB);

    // Hp rows are wave-local (b_ = tid>>3) -> wave-scope lgkmcnt suffices, NO barrier
    Hp[b_ * 16 + u0] = f2bf(hA);
    Hp[b_ * 16 + u1] = f2bf(hB);
    asm volatile("s_waitcnt lgkmcnt(0)" ::: "memory");
    __builtin_amdgcn_sched_barrier(0);

    if (l < 16) {                                  // publish own wave's 8 rows: 16B chunks
      int row = wv * 8 + (l >> 1);
      bf16x8 hv = *(const bf16x8*)&Hp[row * 16 + (l & 1) * 8];
      u16* dstp = hb + (size_t)(k & 3) * (BATCH * HDIM) + (size_t)row * 512
                + w * 16 + (l & 1) * 8;
      asm volatile("global_store_dwordx4 %0, %1, off sc0 sc1" :: "v"(dstp), "v"(hv) : "memory");
    }

    // output from registers — off the critical path
    size_t obase = ((size_t)t * 32 + b_) * 1024 + (size_t)dir * 512 + w * 16;
    out[obase + u0] = hA;
    out[obase + u1] = hB;
    __syncthreads();                               // barrier 2: throttle next-step polls
  }
#undef LOAD8
#undef WAITV
}

// ---------------------------------------------------------------------------------------
extern "C" void kernel_launch(void* const* d_in, const int* in_sizes, int n_in,
                              void* d_out, int out_size, void* d_ws, size_t ws_size,
                              hipStream_t stream) {
  if (ws_size < WS_NEED) return;

  const float* x     = (const float*)d_in[0];
  const float* h0_f  = (const float*)d_in[1];
  const float* c0_f  = (const float*)d_in[2];
  const float* h0_b  = (const float*)d_in[3];
  const float* c0_b  = (const float*)d_in[4];
  const float* Wih_f = (const float*)d_in[5];
  const float* Whh_f = (const float*)d_in[6];
  const float* b_f   = (const float*)d_in[7];
  const float* Wih_b = (const float*)d_in[8];
  const float* Whh_b = (const float*)d_in[9];
  const float* b_b   = (const float*)d_in[10];

  char* ws = (char*)d_ws;
  u16* xbf   = (u16*)(ws + XBF_OFF);
  u16* wihbf = (u16*)(ws + WIH_OFF);
  u16* whhbf = (u16*)(ws + WHH_OFF);
  u16* xpw   = (u16*)(ws + XP_OFF);
  u16* hbuf  = (u16*)(ws + HBUF_OFF);   // overlays WIH region (dead after gemm_xp)

  prep_kernel<<<4096, 256, 0, stream>>>(
      (const float4*)x, (const float4*)Wih_f, (const float4*)Wih_b,
      (const float4*)Whh_f, (const float4*)Whh_b,
      (ushort4*)xbf, (ushort4*)wihbf, (ushort4*)whhbf);

  dim3 g2(512, 16, 2);
  gemm_xp<<<g2, 256, 0, stream>>>(xbf, wihbf, b_f, b_b, xpw);

  prep2_kernel<<<128, 256, 0, stream>>>(
      (const float4*)h0_f, (const float4*)h0_b, (ushort4*)hbuf);

  lstm_scan<<<64, 256, 0, stream>>>(xpw, whhbf, c0_f, c0_b, hbuf, (float*)d_out);
}

// Round 11
// 7642.651 us; speedup vs baseline: 1.6799x; 1.1519x over previous
//
#include <hip/hip_runtime.h>
#include <hip/hip_bf16.h>
#include <stdint.h>

typedef unsigned short u16;
typedef unsigned int   u32;
typedef unsigned long long u64;

typedef __attribute__((ext_vector_type(4))) float  f32x4;
typedef __attribute__((ext_vector_type(8))) short  bf16x8;
typedef __attribute__((ext_vector_type(8))) unsigned short us8;

#define T_LEN 2048
#define BATCH 32
#define IDIM  512
#define HDIM  512
#define G4    2048
#define MARK  0x7FC0   // bf16 NaN — impossible output of sigm*tanh (both clamped finite)

// workspace layout (bytes)
#define XBF_OFF   0ull            // bf16 x : 67108864 B (dead after gemm_xp)
#define WIH_OFF   67108864ull     // bf16 wih[2][2048][512] (dead after gemm_xp)
#define HBUF_OFF  67108864ull     // h_hist bf16 [2][4][32][512] = 256 KiB, reuses WIH region
#define WHH_OFF   71303168ull     // bf16 whh[2][2048][512]
#define XP_OFF    75497472ull     // bf16 xp[2][T][w:32][b:32][g:4][u:16]
#define WS_NEED   612499968ull

__device__ __forceinline__ u16 f2bf(float f) {
  u32 u = __float_as_uint(f);
  return (u16)((u + 0x7FFFu + ((u >> 16) & 1u)) >> 16);   // RTNE
}
__device__ __forceinline__ float bf2f(u16 h) {
  return __uint_as_float(((u32)h) << 16);
}
__device__ __forceinline__ float sigm(float x) {
  x = fminf(fmaxf(x, -30.f), 30.f);
  return 1.f / (1.f + __expf(-x));
}
__device__ __forceinline__ float tanh_(float x) {
  x = fminf(fmaxf(x, -15.f), 15.f);
  float e = __expf(2.f * x);
  return (e - 1.f) / (e + 1.f);
}

// ---------------- prep: fp32 -> bf16 conversions (x, weights) ----------------
__global__ __launch_bounds__(256) void prep_kernel(
    const float4* __restrict__ x,
    const float4* __restrict__ wihf, const float4* __restrict__ wihb,
    const float4* __restrict__ whhf, const float4* __restrict__ whhb,
    ushort4* __restrict__ xbf, ushort4* __restrict__ wihbf,
    ushort4* __restrict__ whhbf)
{
  const size_t NX = 8388608, NW = 262144;   // float4 units
  const size_t total = NX + 4 * NW;
  size_t stride = (size_t)gridDim.x * blockDim.x;
  for (size_t i = (size_t)blockIdx.x * blockDim.x + threadIdx.x; i < total; i += stride) {
    const float4* src; ushort4* dst; size_t off;
    if (i < NX)                { src = x;    dst = xbf;          off = i; }
    else if (i < NX + NW)      { src = wihf; dst = wihbf;        off = i - NX; }
    else if (i < NX + 2 * NW)  { src = wihb; dst = wihbf + NW;   off = i - NX - NW; }
    else if (i < NX + 3 * NW)  { src = whhf; dst = whhbf;        off = i - NX - 2 * NW; }
    else                       { src = whhb; dst = whhbf + NW;   off = i - NX - 3 * NW; }
    float4 v = src[off];
    ushort4 o;
    o.x = f2bf(v.x); o.y = f2bf(v.y); o.z = f2bf(v.z); o.w = f2bf(v.w);
    dst[off] = o;
  }
}

// ---------------- prep2 (runs AFTER gemm_xp): seed h_hist into dead WIH region ------------
// layout: hbuf[dir:2][slot:4][32][512] bf16. slot0 = h0, slots 1..3 = MARK.
__global__ __launch_bounds__(256) void prep2_kernel(
    const float4* __restrict__ h0f, const float4* __restrict__ h0b,
    ushort4* __restrict__ hbuf)
{
  size_t i = (size_t)blockIdx.x * blockDim.x + threadIdx.x;   // 32768 ushort4 total
  if (i >= 32768) return;
  const size_t NH = 4096;          // ushort4 per h0 (32*512 u16)
  const size_t DIR = 16384;        // ushort4 per direction (4 slots)
  size_t d = i / DIR, r = i % DIR;
  ushort4 o;
  if (r < NH) {
    float4 v = (d ? h0b : h0f)[r];
    o.x = f2bf(v.x); o.y = f2bf(v.y); o.z = f2bf(v.z); o.w = f2bf(v.w);
  } else {
    o.x = MARK; o.y = MARK; o.z = MARK; o.w = MARK;
  }
  hbuf[i] = o;
}

// ---------------- x-projection GEMM: xp = x @ Wih^T + b (both dirs), permuted store --------
// M=65536 (t*32+b), N=2048, K=512. 128x128 tile, 4 waves, bf16 MFMA. (R1-proven.)
// Store layout per t: [w:32][b:32][g:4][u:16];  col = g*512 + w*16 + u.
__global__ __launch_bounds__(256, 2) void gemm_xp(
    const u16* __restrict__ xbf, const u16* __restrict__ wihbf,
    const float* __restrict__ bias_f, const float* __restrict__ bias_b,
    u16* __restrict__ xpo)
{
  const int m0 = blockIdx.x * 128;
  const int n0 = blockIdx.y * 128;
  const int dir = blockIdx.z;
  const int tid = threadIdx.x, l = tid & 63, wv = tid >> 6;

  __shared__ u16 As[128 * 72];
  __shared__ u16 Bs[128 * 72];

  const u16* wih = wihbf + (size_t)dir * G4 * IDIM;

  f32x4 acc[4][4];
#pragma unroll
  for (int i = 0; i < 4; i++)
#pragma unroll
    for (int j = 0; j < 4; j++) acc[i][j] = (f32x4){0.f, 0.f, 0.f, 0.f};

  const int srow = tid >> 1, shalf = tid & 1;
  const int wr = wv >> 1, wc = wv & 1;

  for (int k0 = 0; k0 < IDIM; k0 += 64) {
    __syncthreads();
    {
      const u16* ag = xbf + (size_t)(m0 + srow) * IDIM + k0 + shalf * 32;
      const u16* bg = wih + (size_t)(n0 + srow) * IDIM + k0 + shalf * 32;
      u16* ad = &As[srow * 72 + shalf * 32];
      u16* bd = &Bs[srow * 72 + shalf * 32];
#pragma unroll
      for (int q = 0; q < 4; q++) *(us8*)(ad + q * 8) = *(const us8*)(ag + q * 8);
#pragma unroll
      for (int q = 0; q < 4; q++) *(us8*)(bd + q * 8) = *(const us8*)(bg + q * 8);
    }
    __syncthreads();
#pragma unroll
    for (int kk = 0; kk < 2; kk++) {
      bf16x8 af[4], bv[4];
#pragma unroll
      for (int i = 0; i < 4; i++)
        af[i] = *(const bf16x8*)&As[(wr * 64 + i * 16 + (l & 15)) * 72 + kk * 32 + (l >> 4) * 8];
#pragma unroll
      for (int j = 0; j < 4; j++)
        bv[j] = *(const bf16x8*)&Bs[(wc * 64 + j * 16 + (l & 15)) * 72 + kk * 32 + (l >> 4) * 8];
#pragma unroll
      for (int i = 0; i < 4; i++)
#pragma unroll
        for (int j = 0; j < 4; j++)
          acc[i][j] = __builtin_amdgcn_mfma_f32_16x16x32_bf16(af[i], bv[j], acc[i][j], 0, 0, 0);
    }
  }

  const float* bias = dir ? bias_b : bias_f;
  const size_t dirbase = (size_t)dir * T_LEN * 65536ull;
#pragma unroll
  for (int j = 0; j < 4; j++) {
    int col = n0 + wc * 64 + j * 16 + (l & 15);
    float bb = bias[col];
    // col = g*512 + w*16 + u  ->  [w:32][b:32][g:4][u:16]
    size_t coloff = (size_t)((col >> 4) & 31) * 2048 + (size_t)(col >> 9) * 16 + (size_t)(col & 15);
#pragma unroll
    for (int i = 0; i < 4; i++) {
#pragma unroll
      for (int r = 0; r < 4; r++) {
        int row = m0 + wr * 64 + i * 16 + (l >> 4) * 4 + r;
        int t = row >> 5, b = row & 31;
        xpo[dirbase + (size_t)t * 65536 + coloff + (size_t)b * 64] = f2bf(acc[i][j][r] + bb);
      }
    }
  }
}

// ---------------- persistent recurrent scan: data-is-the-flag (R4 protocol) --------------
// 64 WGs: dir = bid>>5, w = bid&31. WG owns 16 hidden units x 32 batches.
// Whh slice (64 gate-rows x 512) lives entirely in registers (128 VGPR/lane).
// 4 waves = (mt: batch-half, kh: K-half). Wave (mt,kh): gates[16 batches, 64 cols] partial
// over its 256-wide K-half; cross-wave K-reduction through LDS.
// Poll: 8x16B chunk loads sc0 sc1; retry only lanes still holding a MARK chunk.
// Publish/clear: fire-and-forget sc0 sc1; slot (k+2)&3 re-markered (ordering proof = R4).
__global__ __launch_bounds__(256, 1) void lstm_scan(
    const u16* __restrict__ xp, const u16* __restrict__ whhbf,
    const float* __restrict__ c0f, const float* __restrict__ c0b,
    u16* hbuf, float* __restrict__ out)
{
  const int bid = blockIdx.x;
  const int dir = bid >> 5;
  const int w   = bid & 31;
  const int tid = threadIdx.x, l = tid & 63, wv = tid >> 6;
  const int mt = wv >> 1, kh = wv & 1;        // batch-half, K-half
  const int grp = l >> 4, lr = l & 15;

  __shared__ float Gl[2][32][68];             // [kh][batch][g*16+u], padded
  __shared__ __align__(16) u16 Hp[512];       // [b][u:16]

  // Whh fragments straight to registers: gate g, K-subtile kk (this wave's K-half)
  bf16x8 bfr[4][8];
#pragma unroll
  for (int g = 0; g < 4; g++) {
    const u16* wrow = whhbf + ((size_t)dir * G4 + (size_t)g * 512 + w * 16 + lr) * 512
                    + kh * 256 + grp * 8;
#pragma unroll
    for (int kk = 0; kk < 8; kk++)
      bfr[g][kk] = *(const bf16x8*)(wrow + kk * 32);
  }

  const int b_ = tid >> 3, u0 = tid & 7;      // elementwise: batch b_, units u0 and u0+8
  const float* c0 = dir ? c0b : c0f;
  float cA = c0[b_ * 512 + w * 16 + u0];
  float cB = c0[b_ * 512 + w * 16 + u0 + 8];

  u16* hb = hbuf + (size_t)dir * 4 * BATCH * HDIM;   // 4 slots
  const u16* xpd = xp + (size_t)dir * T_LEN * 65536ull;
  const int arow = mt * 16 + lr;

  bf16x8 mkv;
#pragma unroll
  for (int q = 0; q < 8; q++) mkv[q] = (short)MARK;

#define LOAD8                                                              \
    asm volatile(                                                          \
      "global_load_dwordx4 %0, %8, off sc0 sc1\n\t"                        \
      "global_load_dwordx4 %1, %8, off offset:64 sc0 sc1\n\t"              \
      "global_load_dwordx4 %2, %8, off offset:128 sc0 sc1\n\t"             \
      "global_load_dwordx4 %3, %8, off offset:192 sc0 sc1\n\t"             \
      "global_load_dwordx4 %4, %8, off offset:256 sc0 sc1\n\t"             \
      "global_load_dwordx4 %5, %8, off offset:320 sc0 sc1\n\t"             \
      "global_load_dwordx4 %6, %8, off offset:384 sc0 sc1\n\t"             \
      "global_load_dwordx4 %7, %8, off offset:448 sc0 sc1\n\t"             \
      "s_waitcnt vmcnt(0)"                                                 \
      : "=&v"(afr[0]), "=&v"(afr[1]), "=&v"(afr[2]), "=&v"(afr[3]),        \
        "=&v"(afr[4]), "=&v"(afr[5]), "=&v"(afr[6]), "=&v"(afr[7])         \
      : "v"(pbase) : "memory")

  for (int k = 1; k <= T_LEN; k++) {
    const int t = dir ? (T_LEN - k) : (k - 1);

    // xp prefetch: 8 gate pre-activations (units u0, u0+8), plain cached loads
    const u16* xb = xpd + (size_t)t * 65536 + (size_t)w * 2048 + (size_t)b_ * 64 + u0;
    u16 xi0 = xb[0],  xiB = xb[8];
    u16 xf0 = xb[16], xfB = xb[24];
    u16 xg0 = xb[32], xgB = xb[40];
    u16 xo0 = xb[48], xoB = xb[56];

    // poll-load h_{k-1}: 8 x 16B chunks; straggler-masked retries
    const u16* pbase = hb + (size_t)((k - 1) & 3) * (BATCH * HDIM)
                     + (size_t)arow * 512 + kh * 256 + grp * 8;
    bf16x8 afr[8];
    LOAD8;
    for (;;) {
      int bad = 0;
#pragma unroll
      for (int q = 0; q < 8; q++) bad |= (afr[q][0] == (short)MARK);
      if (!__any(bad)) break;
      __builtin_amdgcn_s_sleep(2);
      if (bad) { LOAD8; }
    }
    __builtin_amdgcn_sched_barrier(0);

    f32x4 acc[4];
#pragma unroll
    for (int g = 0; g < 4; g++) acc[g] = (f32x4){0.f, 0.f, 0.f, 0.f};
#pragma unroll
    for (int kk = 0; kk < 8; kk++) {
#pragma unroll
      for (int g = 0; g < 4; g++)
        acc[g] = __builtin_amdgcn_mfma_f32_16x16x32_bf16(afr[kk], bfr[g][kk], acc[g], 0, 0, 0);
    }
#pragma unroll
    for (int g = 0; g < 4; g++)
#pragma unroll
      for (int r = 0; r < 4; r++)
        Gl[kh][mt * 16 + grp * 4 + r][g * 16 + lr] = acc[g][r];
    __syncthreads();                               // gates ready

    // elementwise: two units per thread
    float ai = Gl[0][b_][u0]      + Gl[1][b_][u0]      + bf2f(xi0);
    float af = Gl[0][b_][16 + u0] + Gl[1][b_][16 + u0] + bf2f(xf0);
    float ag = Gl[0][b_][32 + u0] + Gl[1][b_][32 + u0] + bf2f(xg0);
    float ao = Gl[0][b_][48 + u0] + Gl[1][b_][48 + u0] + bf2f(xo0);
    float si = sigm(ai), sf_ = sigm(af), sg = tanh_(ag), so = sigm(ao);
    cA = sf_ * cA + si * sg;
    float hA = so * tanh_(cA);

    const int u1 = u0 + 8;
    ai = Gl[0][b_][u1]      + Gl[1][b_][u1]      + bf2f(xiB);
    af = Gl[0][b_][16 + u1] + Gl[1][b_][16 + u1] + bf2f(xfB);
    ag = Gl[0][b_][32 + u1] + Gl[1][b_][32 + u1] + bf2f(xgB);
    ao = Gl[0][b_][48 + u1] + Gl[1][b_][48 + u1] + bf2f(xoB);
    si = sigm(ai); sf_ = sigm(af); sg = tanh_(ag); so = sigm(ao);
    cB = sf_ * cB + si * sg;
    float hB = so * tanh_(cB);

    Hp[b_ * 16 + u0] = f2bf(hA);
    Hp[b_ * 16 + u1] = f2bf(hB);
    __syncthreads();                               // Hp packed

    if (wv == 0) {                                 // publish h_k: 64 x 16B, fire-and-forget
      bf16x8 hv = *(const bf16x8*)&Hp[l * 8];
      u16* dstp = hb + (size_t)(k & 3) * (BATCH * HDIM) + (size_t)(l >> 1) * 512
                + w * 16 + (l & 1) * 8;
      asm volatile("global_store_dwordx4 %0, %1, off sc0 sc1" :: "v"(dstp), "v"(hv) : "memory");
    }
    if (wv == 1) {                                 // re-marker slot (k+2)&3 (own slice)
      u16* cdst = hb + (size_t)((k + 2) & 3) * (BATCH * HDIM) + (size_t)(l >> 1) * 512
                + w * 16 + (l & 1) * 8;
      asm volatile("global_store_dwordx4 %0, %1, off sc0 sc1" :: "v"(cdst), "v"(mkv) : "memory");
    }

    // output from registers — off the critical path
    size_t obase = ((size_t)t * 32 + b_) * 1024 + (size_t)dir * 512 + w * 16;
    out[obase + u0] = hA;
    out[obase + u1] = hB;
  }
#undef LOAD8
}

// ---------------------------------------------------------------------------------------
extern "C" void kernel_launch(void* const* d_in, const int* in_sizes, int n_in,
                              void* d_out, int out_size, void* d_ws, size_t ws_size,
                              hipStream_t stream) {
  if (ws_size < WS_NEED) return;

  const float* x     = (const float*)d_in[0];
  const float* h0_f  = (const float*)d_in[1];
  const float* c0_f  = (const float*)d_in[2];
  const float* h0_b  = (const float*)d_in[3];
  const float* c0_b  = (const float*)d_in[4];
  const float* Wih_f = (const float*)d_in[5];
  const float* Whh_f = (const float*)d_in[6];
  const float* b_f   = (const float*)d_in[7];
  const float* Wih_b = (const float*)d_in[8];
  const float* Whh_b = (const float*)d_in[9];
  const float* b_b   = (const float*)d_in[10];

  char* ws = (char*)d_ws;
  u16* xbf   = (u16*)(ws + XBF_OFF);
  u16* wihbf = (u16*)(ws + WIH_OFF);
  u16* whhbf = (u16*)(ws + WHH_OFF);
  u16* xpw   = (u16*)(ws + XP_OFF);
  u16* hbuf  = (u16*)(ws + HBUF_OFF);   // overlays WIH region (dead after gemm_xp)

  prep_kernel<<<4096, 256, 0, stream>>>(
      (const float4*)x, (const float4*)Wih_f, (const float4*)Wih_b,
      (const float4*)Whh_f, (const float4*)Whh_b,
      (ushort4*)xbf, (ushort4*)wihbf, (ushort4*)whhbf);

  dim3 g2(512, 16, 2);
  gemm_xp<<<g2, 256, 0, stream>>>(xbf, wihbf, b_f, b_b, xpw);

  prep2_kernel<<<128, 256, 0, stream>>>(
      (const float4*)h0_f, (const float4*)h0_b, (ushort4*)hbuf);

  lstm_scan<<<64, 256, 0, stream>>>(xpw, whhbf, c0_f, c0_b, hbuf, (float*)d_out);
}